// Round 1
// baseline (9447.422 us; speedup 1.0000x reference)
//
#include <hip/hip_runtime.h>

#define NPAPER 200000
#define NMESH  30000
#define NNODES 230000
#define ETRAIN 2000000
#define EPOS   500000
#define ENEG   500000

__device__ __forceinline__ void fma4(float4& a, float s, const float4 w) {
    a.x = fmaf(s, w.x, a.x);
    a.y = fmaf(s, w.y, a.y);
    a.z = fmaf(s, w.z, a.z);
    a.w = fmaf(s, w.w, a.w);
}

// ---------------- encode: out[row][0:16] = x[row][:] @ W + b ----------------
// one wave per row; W staged in LDS with row stride 20 (16B-aligned quads,
// 17*? -> 20 gives 2-way-max bank aliasing which is free on gfx950)
template <int D>
__global__ __launch_bounds__(256) void encode_kernel(
    const float* __restrict__ x, const float* __restrict__ w,
    const float* __restrict__ bias, float* __restrict__ out, int nrows) {
    __shared__ float wlds[D * 20];
    __shared__ float blds[16];
    for (int i = threadIdx.x; i < D * 16; i += 256)
        wlds[(i >> 4) * 20 + (i & 15)] = w[i];
    if (threadIdx.x < 16) blds[threadIdx.x] = bias[threadIdx.x];
    __syncthreads();

    const int lane = threadIdx.x & 63;
    const int row = blockIdx.x * 4 + (threadIdx.x >> 6);
    if (row >= nrows) return;

    const float* xr = x + (size_t)row * D;
    float4 acc[4];
#pragma unroll
    for (int g = 0; g < 4; g++) acc[g] = make_float4(0.f, 0.f, 0.f, 0.f);

#pragma unroll
    for (int t = 0; t < D / 64; t++) {
        const float xv = xr[t * 64 + lane];
        const float* wr = wlds + (t * 64 + lane) * 20;
#pragma unroll
        for (int g = 0; g < 4; g++)
            fma4(acc[g], xv, *reinterpret_cast<const float4*>(wr + 4 * g));
    }

    // full 64-lane butterfly reduce; afterwards every lane holds the sums
#pragma unroll
    for (int g = 0; g < 4; g++) {
#pragma unroll
        for (int off = 32; off; off >>= 1) {
            acc[g].x += __shfl_xor(acc[g].x, off);
            acc[g].y += __shfl_xor(acc[g].y, off);
            acc[g].z += __shfl_xor(acc[g].z, off);
            acc[g].w += __shfl_xor(acc[g].w, off);
        }
    }
    if (lane == 0) {
        float4* orow = reinterpret_cast<float4*>(out + (size_t)row * 16);
#pragma unroll
        for (int g = 0; g < 4; g++) {
            const float4 b4 = *reinterpret_cast<const float4*>(blds + 4 * g);
            float4 o;
            o.x = acc[g].x + b4.x;
            o.y = acc[g].y + b4.y;
            o.z = acc[g].z + b4.z;
            o.w = acc[g].w + b4.w;
            orow[g] = o;
        }
    }
}

// ---------------- degree ----------------
__global__ __launch_bounds__(256) void deg_kernel(const int* __restrict__ dst,
                                                  float* __restrict__ deg) {
    const int e = blockIdx.x * 256 + threadIdx.x;
    if (e >= ETRAIN) return;
    atomicAdd(deg + dst[e], 1.0f);
}

// ---------------- per-edge message + scatter-add ----------------
// m = x[src] @ W[etype]; atomicAdd(agg[dst], m).  W (both relations) built
// from comp/basis into LDS once per block.
template <int IN, int OUT>
__global__ __launch_bounds__(256) void scatter_kernel(
    const float* __restrict__ x, const int* __restrict__ src,
    const int* __restrict__ dst, const int* __restrict__ et,
    const float* __restrict__ comp, const float* __restrict__ basis,
    float* __restrict__ agg) {
    __shared__ float wlds[2 * IN * OUT];
    for (int i = threadIdx.x; i < 2 * IN * OUT; i += 256) {
        const int r = i / (IN * OUT);
        const int rem = i - r * IN * OUT;
        float v = 0.f;
#pragma unroll
        for (int b = 0; b < 4; b++)
            v = fmaf(comp[r * 4 + b], basis[b * IN * OUT + rem], v);
        wlds[i] = v;
    }
    __syncthreads();

    const int e = blockIdx.x * 256 + threadIdx.x;
    if (e >= ETRAIN) return;
    const int s = src[e], d = dst[e], t = et[e];

    const float4* xr = reinterpret_cast<const float4*>(x + (size_t)s * IN);
    float4 xv[IN / 4];
#pragma unroll
    for (int q = 0; q < IN / 4; q++) xv[q] = xr[q];

    const float* W = wlds + t * IN * OUT;
    float4 acc[OUT / 4];
#pragma unroll
    for (int g = 0; g < OUT / 4; g++) acc[g] = make_float4(0.f, 0.f, 0.f, 0.f);

#pragma unroll
    for (int q = 0; q < IN / 4; q++) {
        const float xs[4] = {xv[q].x, xv[q].y, xv[q].z, xv[q].w};
#pragma unroll
        for (int c = 0; c < 4; c++) {
            const float xk = xs[c];
            const float4* wr =
                reinterpret_cast<const float4*>(W + (q * 4 + c) * OUT);
#pragma unroll
            for (int g = 0; g < OUT / 4; g++) fma4(acc[g], xk, wr[g]);
        }
    }

    float* ar = agg + (size_t)d * OUT;
#pragma unroll
    for (int g = 0; g < OUT / 4; g++) {
        atomicAdd(ar + 4 * g + 0, acc[g].x);
        atomicAdd(ar + 4 * g + 1, acc[g].y);
        atomicAdd(ar + 4 * g + 2, acc[g].z);
        atomicAdd(ar + 4 * g + 3, acc[g].w);
    }
}

// ---------------- combine: out = agg/max(deg,1) + x@root + bias (opt relu) --
template <int IN, int OUT, bool RELU>
__global__ __launch_bounds__(256) void combine_kernel(
    const float* __restrict__ xin, const float* __restrict__ agg,
    const float* __restrict__ deg, const float* __restrict__ root,
    const float* __restrict__ bias, float* __restrict__ out) {
    constexpr int QP = OUT / 4;
    __shared__ float rlds[IN * OUT];
    __shared__ float blds[OUT];
    for (int i = threadIdx.x; i < IN * OUT; i += 256) rlds[i] = root[i];
    if (threadIdx.x < OUT) blds[threadIdx.x] = bias[threadIdx.x];
    __syncthreads();

    const int tid = blockIdx.x * 256 + threadIdx.x;
    const int n = tid / QP, g = tid % QP;
    if (n >= NNODES) return;

    const float invd = 1.0f / fmaxf(deg[n], 1.0f);
    const float4 a =
        reinterpret_cast<const float4*>(agg + (size_t)n * OUT)[g];
    float4 acc = reinterpret_cast<const float4*>(blds)[g];
    acc.x = fmaf(a.x, invd, acc.x);
    acc.y = fmaf(a.y, invd, acc.y);
    acc.z = fmaf(a.z, invd, acc.z);
    acc.w = fmaf(a.w, invd, acc.w);

    const float* xr = xin + (size_t)n * IN;
#pragma unroll
    for (int k = 0; k < IN; k++)
        fma4(acc, xr[k], reinterpret_cast<const float4*>(rlds + k * OUT)[g]);

    if (RELU) {
        acc.x = fmaxf(acc.x, 0.f);
        acc.y = fmaxf(acc.y, 0.f);
        acc.z = fmaxf(acc.z, 0.f);
        acc.w = fmaxf(acc.w, 0.f);
    }
    reinterpret_cast<float4*>(out + (size_t)n * OUT)[g] = acc;
}

// ---------------- decode: score = ((zs @ W[t]) + b[t]) . zd ----------------
__global__ __launch_bounds__(256) void decode_kernel(
    const float* __restrict__ z, const int* __restrict__ ei,
    const int* __restrict__ et, const float* __restrict__ wp,
    const float* __restrict__ bp, const float* __restrict__ wm,
    const float* __restrict__ bm, float* __restrict__ out, int E) {
    __shared__ float wl[2 * 256];
    __shared__ float bl[2 * 16];
    {
        const int i = threadIdx.x;
        wl[i] = wp[i];
        wl[256 + i] = wm[i];
        if (i < 16) {
            bl[i] = bp[i];
            bl[16 + i] = bm[i];
        }
    }
    __syncthreads();

    const int e = blockIdx.x * 256 + threadIdx.x;
    if (e >= E) return;
    const int s = ei[e], d = ei[e + E], t = et[e];

    const float4* zs4 = reinterpret_cast<const float4*>(z + (size_t)s * 16);
    const float4* zd4 = reinterpret_cast<const float4*>(z + (size_t)d * 16);
    float4 zs[4], zd[4];
#pragma unroll
    for (int q = 0; q < 4; q++) {
        zs[q] = zs4[q];
        zd[q] = zd4[q];
    }

    const float* W = wl + t * 256;
    const float* B = bl + t * 16;
    float4 p[4];
#pragma unroll
    for (int g = 0; g < 4; g++)
        p[g] = reinterpret_cast<const float4*>(B)[g];

#pragma unroll
    for (int q = 0; q < 4; q++) {
        const float xs[4] = {zs[q].x, zs[q].y, zs[q].z, zs[q].w};
#pragma unroll
        for (int c = 0; c < 4; c++) {
            const float4* wr =
                reinterpret_cast<const float4*>(W + (q * 4 + c) * 16);
#pragma unroll
            for (int g = 0; g < 4; g++) fma4(p[g], xs[c], wr[g]);
        }
    }
    float sc = 0.f;
#pragma unroll
    for (int g = 0; g < 4; g++) {
        sc += p[g].x * zd[g].x + p[g].y * zd[g].y + p[g].z * zd[g].z +
              p[g].w * zd[g].w;
    }
    out[e] = sc;
}

extern "C" void kernel_launch(void* const* d_in, const int* in_sizes, int n_in,
                              void* d_out, int out_size, void* d_ws,
                              size_t ws_size, hipStream_t stream) {
    const float* x_paper = (const float*)d_in[0];
    const float* x_mesh = (const float*)d_in[1];
    const float* tp_w = (const float*)d_in[2];
    const float* tp_b = (const float*)d_in[3];
    const float* tm_w = (const float*)d_in[4];
    const float* tm_b = (const float*)d_in[5];
    const float* comp1 = (const float*)d_in[6];
    const float* basis1 = (const float*)d_in[7];
    const float* root1 = (const float*)d_in[8];
    const float* bias1 = (const float*)d_in[9];
    const float* comp2 = (const float*)d_in[10];
    const float* basis2 = (const float*)d_in[11];
    const float* root2 = (const float*)d_in[12];
    const float* bias2 = (const float*)d_in[13];
    const float* comp3 = (const float*)d_in[14];
    const float* basis3 = (const float*)d_in[15];
    const float* root3 = (const float*)d_in[16];
    const float* bias3 = (const float*)d_in[17];
    const float* dpp_w = (const float*)d_in[18];
    const float* dpp_b = (const float*)d_in[19];
    const float* dpm_w = (const float*)d_in[20];
    const float* dpm_b = (const float*)d_in[21];
    const int* tei = (const int*)d_in[22];
    const int* tet = (const int*)d_in[23];
    const int* pei = (const int*)d_in[24];
    const int* pet = (const int*)d_in[25];
    const int* nei = (const int*)d_in[26];
    const int* net = (const int*)d_in[27];
    float* out = (float*)d_out;

    // workspace layout (floats)
    float* ws = (float*)d_ws;
    float* xfeat = ws;                         // N*16  (reused as z)
    float* h1 = xfeat + (size_t)NNODES * 16;   // N*32
    float* h2 = h1 + (size_t)NNODES * 32;      // N*32
    float* agg = h2 + (size_t)NNODES * 32;     // N*32
    float* deg = agg + (size_t)NNODES * 32;    // N
    float* z = xfeat;

    const int* tsrc = tei;
    const int* tdst = tei + ETRAIN;

    // ---- encode ----
    encode_kernel<512><<<(NPAPER + 3) / 4, 256, 0, stream>>>(
        x_paper, tp_w, tp_b, xfeat, NPAPER);
    encode_kernel<128><<<(NMESH + 3) / 4, 256, 0, stream>>>(
        x_mesh, tm_w, tm_b, xfeat + (size_t)NPAPER * 16, NMESH);

    // ---- degree (shared across layers) ----
    hipMemsetAsync(deg, 0, (size_t)NNODES * 4, stream);
    deg_kernel<<<(ETRAIN + 255) / 256, 256, 0, stream>>>(tdst, deg);

    const int eblocks = (ETRAIN + 255) / 256;

    // ---- layer 1: 16 -> 32, relu ----
    hipMemsetAsync(agg, 0, (size_t)NNODES * 32 * 4, stream);
    scatter_kernel<16, 32><<<eblocks, 256, 0, stream>>>(
        xfeat, tsrc, tdst, tet, comp1, basis1, agg);
    combine_kernel<16, 32, true>
        <<<(NNODES * 8 + 255) / 256, 256, 0, stream>>>(xfeat, agg, deg, root1,
                                                       bias1, h1);

    // ---- layer 2: 32 -> 32, relu ----
    hipMemsetAsync(agg, 0, (size_t)NNODES * 32 * 4, stream);
    scatter_kernel<32, 32><<<eblocks, 256, 0, stream>>>(
        h1, tsrc, tdst, tet, comp2, basis2, agg);
    combine_kernel<32, 32, true>
        <<<(NNODES * 8 + 255) / 256, 256, 0, stream>>>(h1, agg, deg, root2,
                                                       bias2, h2);

    // ---- layer 3: 32 -> 16, no relu ----
    hipMemsetAsync(agg, 0, (size_t)NNODES * 16 * 4, stream);
    scatter_kernel<32, 16><<<eblocks, 256, 0, stream>>>(
        h2, tsrc, tdst, tet, comp3, basis3, agg);
    combine_kernel<32, 16, false>
        <<<(NNODES * 4 + 255) / 256, 256, 0, stream>>>(h2, agg, deg, root3,
                                                       bias3, z);

    // ---- decode ----
    decode_kernel<<<(EPOS + 255) / 256, 256, 0, stream>>>(
        z, pei, pet, dpp_w, dpp_b, dpm_w, dpm_b, out, EPOS);
    decode_kernel<<<(ENEG + 255) / 256, 256, 0, stream>>>(
        z, nei, net, dpp_w, dpp_b, dpm_w, dpm_b, out + EPOS, ENEG);
}

// Round 2
// 1365.324 us; speedup vs baseline: 6.9195x; 6.9195x over previous
//
#include <hip/hip_runtime.h>

#define NPAPER 200000
#define NMESH  30000
#define NNODES 230000
#define ETRAIN 2000000
#define EPOS   500000
#define ENEG   500000

__device__ __forceinline__ void fma4(float4& a, float s, const float4 w) {
    a.x = fmaf(s, w.x, a.x);
    a.y = fmaf(s, w.y, a.y);
    a.z = fmaf(s, w.z, a.z);
    a.w = fmaf(s, w.w, a.w);
}

// ---------------- encode: out[row][0:16] = x[row][:] @ W + b ----------------
template <int D>
__global__ __launch_bounds__(256) void encode_kernel(
    const float* __restrict__ x, const float* __restrict__ w,
    const float* __restrict__ bias, float* __restrict__ out, int nrows) {
    __shared__ float wlds[D * 20];
    __shared__ float blds[16];
    for (int i = threadIdx.x; i < D * 16; i += 256)
        wlds[(i >> 4) * 20 + (i & 15)] = w[i];
    if (threadIdx.x < 16) blds[threadIdx.x] = bias[threadIdx.x];
    __syncthreads();

    const int lane = threadIdx.x & 63;
    const int row = blockIdx.x * 4 + (threadIdx.x >> 6);
    if (row >= nrows) return;

    const float* xr = x + (size_t)row * D;
    float4 acc[4];
#pragma unroll
    for (int g = 0; g < 4; g++) acc[g] = make_float4(0.f, 0.f, 0.f, 0.f);

#pragma unroll
    for (int t = 0; t < D / 64; t++) {
        const float xv = xr[t * 64 + lane];
        const float* wr = wlds + (t * 64 + lane) * 20;
#pragma unroll
        for (int g = 0; g < 4; g++)
            fma4(acc[g], xv, *reinterpret_cast<const float4*>(wr + 4 * g));
    }

#pragma unroll
    for (int g = 0; g < 4; g++) {
#pragma unroll
        for (int off = 32; off; off >>= 1) {
            acc[g].x += __shfl_xor(acc[g].x, off);
            acc[g].y += __shfl_xor(acc[g].y, off);
            acc[g].z += __shfl_xor(acc[g].z, off);
            acc[g].w += __shfl_xor(acc[g].w, off);
        }
    }
    if (lane == 0) {
        float4* orow = reinterpret_cast<float4*>(out + (size_t)row * 16);
#pragma unroll
        for (int g = 0; g < 4; g++) {
            const float4 b4 = *reinterpret_cast<const float4*>(blds + 4 * g);
            float4 o;
            o.x = acc[g].x + b4.x;
            o.y = acc[g].y + b4.y;
            o.z = acc[g].z + b4.z;
            o.w = acc[g].w + b4.w;
            orow[g] = o;
        }
    }
}

// ---------------- CSR construction ----------------
__global__ __launch_bounds__(256) void hist_kernel(const int* __restrict__ dst,
                                                   int* __restrict__ cnt) {
    const int e = blockIdx.x * 256 + threadIdx.x;
    if (e >= ETRAIN) return;
    atomicAdd(cnt + dst[e], 1);
}

// per-block exclusive scan; block sums to bsum
__global__ __launch_bounds__(256) void scan1_kernel(const int* __restrict__ in,
                                                    int* __restrict__ out,
                                                    int* __restrict__ bsum,
                                                    int n) {
    __shared__ int s[256];
    const int tid = threadIdx.x;
    const int i = blockIdx.x * 256 + tid;
    const int v = (i < n) ? in[i] : 0;
    s[tid] = v;
    __syncthreads();
#pragma unroll
    for (int off = 1; off < 256; off <<= 1) {
        const int t = (tid >= off) ? s[tid - off] : 0;
        __syncthreads();
        s[tid] += t;
        __syncthreads();
    }
    if (i < n) out[i] = s[tid] - v;
    if (tid == 255) bsum[blockIdx.x] = s[255];
}

// single-block sequential-chunk exclusive scan of bsum
__global__ __launch_bounds__(256) void scan2_kernel(int* __restrict__ bsum,
                                                    int nb) {
    __shared__ int s[256];
    const int tid = threadIdx.x;
    int carry = 0;
    for (int base = 0; base < nb; base += 256) {
        const int i = base + tid;
        const int v = (i < nb) ? bsum[i] : 0;
        s[tid] = v;
        __syncthreads();
#pragma unroll
        for (int off = 1; off < 256; off <<= 1) {
            const int t = (tid >= off) ? s[tid - off] : 0;
            __syncthreads();
            s[tid] += t;
            __syncthreads();
        }
        if (i < nb) bsum[i] = s[tid] - v + carry;
        const int tot = s[255];
        __syncthreads();
        carry += tot;
    }
}

__global__ __launch_bounds__(256) void scan3_kernel(int* __restrict__ out,
                                                    const int* __restrict__ bsum,
                                                    int n) {
    const int i = blockIdx.x * 256 + threadIdx.x;
    if (i < n) out[i] += bsum[blockIdx.x];
}

// scatter edges into dst-sorted order; payload = src | (etype << 24)
__global__ __launch_bounds__(256) void fill_kernel(
    const int* __restrict__ src, const int* __restrict__ dst,
    const int* __restrict__ et, const int* __restrict__ rowptr,
    int* __restrict__ fc, int* __restrict__ esorted) {
    const int e = blockIdx.x * 256 + threadIdx.x;
    if (e >= ETRAIN) return;
    const int d = dst[e];
    const int pos = rowptr[d] + atomicAdd(fc + d, 1);
    esorted[pos] = src[e] | (et[e] << 24);
}

// ---------------- fused RGCN layer (gather form) ----------------
// thread owns (node n, 4 output cols starting at 4g); OUT/4 threads per node.
// out[n] = relu?( mean_{e->n}( x[src_e] @ W[t_e] ) + x[n] @ root + bias )
template <int IN, int OUT, bool RELU>
__global__ __launch_bounds__(256) void rgcn_gather_kernel(
    const float* __restrict__ x, const int* __restrict__ rowptr,
    const int* __restrict__ cnt, const int* __restrict__ esorted,
    const float* __restrict__ comp, const float* __restrict__ basis,
    const float* __restrict__ root, const float* __restrict__ bias,
    float* __restrict__ out) {
    constexpr int QP = OUT / 4;
    __shared__ float wlds[2 * IN * OUT];
    __shared__ float rlds[IN * OUT];
    __shared__ float blds[OUT];
    for (int i = threadIdx.x; i < 2 * IN * OUT; i += 256) {
        const int r = i / (IN * OUT);
        const int rem = i - r * IN * OUT;
        float v = 0.f;
#pragma unroll
        for (int b = 0; b < 4; b++)
            v = fmaf(comp[r * 4 + b], basis[b * IN * OUT + rem], v);
        wlds[i] = v;
    }
    for (int i = threadIdx.x; i < IN * OUT; i += 256) rlds[i] = root[i];
    if (threadIdx.x < OUT) blds[threadIdx.x] = bias[threadIdx.x];
    __syncthreads();

    const int gtid = blockIdx.x * 256 + threadIdx.x;
    const int n = gtid / QP;
    const int g = gtid % QP;
    if (n >= NNODES) return;

    const int begin = rowptr[n];
    const int c = cnt[n];

    float4 acc = make_float4(0.f, 0.f, 0.f, 0.f);
    for (int i = 0; i < c; i++) {
        const int pk = esorted[begin + i];
        const int s = pk & 0x00FFFFFF;
        const float* Wt = wlds + (pk >> 24) * (IN * OUT);
        const float4* xs = reinterpret_cast<const float4*>(x + (size_t)s * IN);
#pragma unroll
        for (int q = 0; q < IN / 4; q++) {
            const float4 xv = xs[q];
            const float* wq = Wt + (q * 4) * OUT + 4 * g;
            fma4(acc, xv.x, *reinterpret_cast<const float4*>(wq));
            fma4(acc, xv.y, *reinterpret_cast<const float4*>(wq + OUT));
            fma4(acc, xv.z, *reinterpret_cast<const float4*>(wq + 2 * OUT));
            fma4(acc, xv.w, *reinterpret_cast<const float4*>(wq + 3 * OUT));
        }
    }
    const float inv = 1.0f / fmaxf((float)c, 1.0f);
    float4 o = *reinterpret_cast<const float4*>(blds + 4 * g);
    o.x = fmaf(acc.x, inv, o.x);
    o.y = fmaf(acc.y, inv, o.y);
    o.z = fmaf(acc.z, inv, o.z);
    o.w = fmaf(acc.w, inv, o.w);

    const float4* xn = reinterpret_cast<const float4*>(x + (size_t)n * IN);
#pragma unroll
    for (int q = 0; q < IN / 4; q++) {
        const float4 xv = xn[q];
        const float* rq = rlds + (q * 4) * OUT + 4 * g;
        fma4(o, xv.x, *reinterpret_cast<const float4*>(rq));
        fma4(o, xv.y, *reinterpret_cast<const float4*>(rq + OUT));
        fma4(o, xv.z, *reinterpret_cast<const float4*>(rq + 2 * OUT));
        fma4(o, xv.w, *reinterpret_cast<const float4*>(rq + 3 * OUT));
    }
    if (RELU) {
        o.x = fmaxf(o.x, 0.f);
        o.y = fmaxf(o.y, 0.f);
        o.z = fmaxf(o.z, 0.f);
        o.w = fmaxf(o.w, 0.f);
    }
    reinterpret_cast<float4*>(out + (size_t)n * OUT)[g] = o;
}

// ---------------- decode: score = ((zs @ W[t]) + b[t]) . zd ----------------
__global__ __launch_bounds__(256) void decode_kernel(
    const float* __restrict__ z, const int* __restrict__ ei,
    const int* __restrict__ et, const float* __restrict__ wp,
    const float* __restrict__ bp, const float* __restrict__ wm,
    const float* __restrict__ bm, float* __restrict__ out, int E) {
    __shared__ float wl[2 * 256];
    __shared__ float bl[2 * 16];
    {
        const int i = threadIdx.x;
        wl[i] = wp[i];
        wl[256 + i] = wm[i];
        if (i < 16) {
            bl[i] = bp[i];
            bl[16 + i] = bm[i];
        }
    }
    __syncthreads();

    const int e = blockIdx.x * 256 + threadIdx.x;
    if (e >= E) return;
    const int s = ei[e], d = ei[e + E], t = et[e];

    const float4* zs4 = reinterpret_cast<const float4*>(z + (size_t)s * 16);
    const float4* zd4 = reinterpret_cast<const float4*>(z + (size_t)d * 16);
    float4 zs[4], zd[4];
#pragma unroll
    for (int q = 0; q < 4; q++) {
        zs[q] = zs4[q];
        zd[q] = zd4[q];
    }

    const float* W = wl + t * 256;
    const float* B = bl + t * 16;
    float4 p[4];
#pragma unroll
    for (int g = 0; g < 4; g++) p[g] = reinterpret_cast<const float4*>(B)[g];

#pragma unroll
    for (int q = 0; q < 4; q++) {
        const float xs[4] = {zs[q].x, zs[q].y, zs[q].z, zs[q].w};
#pragma unroll
        for (int c = 0; c < 4; c++) {
            const float4* wr =
                reinterpret_cast<const float4*>(W + (q * 4 + c) * 16);
#pragma unroll
            for (int g = 0; g < 4; g++) fma4(p[g], xs[c], wr[g]);
        }
    }
    float sc = 0.f;
#pragma unroll
    for (int g = 0; g < 4; g++) {
        sc += p[g].x * zd[g].x + p[g].y * zd[g].y + p[g].z * zd[g].z +
              p[g].w * zd[g].w;
    }
    out[e] = sc;
}

extern "C" void kernel_launch(void* const* d_in, const int* in_sizes, int n_in,
                              void* d_out, int out_size, void* d_ws,
                              size_t ws_size, hipStream_t stream) {
    const float* x_paper = (const float*)d_in[0];
    const float* x_mesh = (const float*)d_in[1];
    const float* tp_w = (const float*)d_in[2];
    const float* tp_b = (const float*)d_in[3];
    const float* tm_w = (const float*)d_in[4];
    const float* tm_b = (const float*)d_in[5];
    const float* comp1 = (const float*)d_in[6];
    const float* basis1 = (const float*)d_in[7];
    const float* root1 = (const float*)d_in[8];
    const float* bias1 = (const float*)d_in[9];
    const float* comp2 = (const float*)d_in[10];
    const float* basis2 = (const float*)d_in[11];
    const float* root2 = (const float*)d_in[12];
    const float* bias2 = (const float*)d_in[13];
    const float* comp3 = (const float*)d_in[14];
    const float* basis3 = (const float*)d_in[15];
    const float* root3 = (const float*)d_in[16];
    const float* bias3 = (const float*)d_in[17];
    const float* dpp_w = (const float*)d_in[18];
    const float* dpp_b = (const float*)d_in[19];
    const float* dpm_w = (const float*)d_in[20];
    const float* dpm_b = (const float*)d_in[21];
    const int* tei = (const int*)d_in[22];
    const int* tet = (const int*)d_in[23];
    const int* pei = (const int*)d_in[24];
    const int* pet = (const int*)d_in[25];
    const int* nei = (const int*)d_in[26];
    const int* net = (const int*)d_in[27];
    float* out = (float*)d_out;

    // workspace layout
    float* ws = (float*)d_ws;
    float* xfeat = ws;                        // N*16  (reused as z)
    float* h1 = xfeat + (size_t)NNODES * 16;  // N*32
    float* h2 = h1 + (size_t)NNODES * 32;     // N*32
    int* rowptr = (int*)(h2 + (size_t)NNODES * 32);  // N
    int* ecnt = rowptr + NNODES;                     // N
    int* fc = ecnt + NNODES;                         // N
    int* esorted = fc + NNODES;                      // E_TRAIN
    int* bsum = esorted + ETRAIN;                    // ~1K
    float* z = xfeat;

    const int* tsrc = tei;
    const int* tdst = tei + ETRAIN;

    const int eblocks = (ETRAIN + 255) / 256;
    const int nb = (NNODES + 255) / 256;  // 899

    // ---- encode ----
    encode_kernel<512><<<(NPAPER + 3) / 4, 256, 0, stream>>>(
        x_paper, tp_w, tp_b, xfeat, NPAPER);
    encode_kernel<128><<<(NMESH + 3) / 4, 256, 0, stream>>>(
        x_mesh, tm_w, tm_b, xfeat + (size_t)NPAPER * 16, NMESH);

    // ---- CSR build (once; reused by all 3 layers) ----
    hipMemsetAsync(ecnt, 0, (size_t)NNODES * 4, stream);
    hipMemsetAsync(fc, 0, (size_t)NNODES * 4, stream);
    hist_kernel<<<eblocks, 256, 0, stream>>>(tdst, ecnt);
    scan1_kernel<<<nb, 256, 0, stream>>>(ecnt, rowptr, bsum, NNODES);
    scan2_kernel<<<1, 256, 0, stream>>>(bsum, nb);
    scan3_kernel<<<nb, 256, 0, stream>>>(rowptr, bsum, NNODES);
    fill_kernel<<<eblocks, 256, 0, stream>>>(tsrc, tdst, tet, rowptr, fc,
                                             esorted);

    // ---- layers ----
    const int g32 = (NNODES * 8 + 255) / 256;
    const int g16 = (NNODES * 4 + 255) / 256;
    rgcn_gather_kernel<16, 32, true><<<g32, 256, 0, stream>>>(
        xfeat, rowptr, ecnt, esorted, comp1, basis1, root1, bias1, h1);
    rgcn_gather_kernel<32, 32, true><<<g32, 256, 0, stream>>>(
        h1, rowptr, ecnt, esorted, comp2, basis2, root2, bias2, h2);
    rgcn_gather_kernel<32, 16, false><<<g16, 256, 0, stream>>>(
        h2, rowptr, ecnt, esorted, comp3, basis3, root3, bias3, z);

    // ---- decode ----
    decode_kernel<<<(EPOS + 255) / 256, 256, 0, stream>>>(
        z, pei, pet, dpp_w, dpp_b, dpm_w, dpm_b, out, EPOS);
    decode_kernel<<<(ENEG + 255) / 256, 256, 0, stream>>>(
        z, nei, net, dpp_w, dpp_b, dpm_w, dpm_b, out + EPOS, ENEG);
}

// Round 3
// 1238.161 us; speedup vs baseline: 7.6302x; 1.1027x over previous
//
#include <hip/hip_runtime.h>

#define NPAPER 200000
#define NMESH  30000
#define NNODES 230000
#define ETRAIN 2000000
#define EPOS   500000
#define ENEG   500000

__device__ __forceinline__ void fma4(float4& a, float s, const float4 w) {
    a.x = fmaf(s, w.x, a.x);
    a.y = fmaf(s, w.y, a.y);
    a.z = fmaf(s, w.z, a.z);
    a.w = fmaf(s, w.w, a.w);
}

// ---------------- encode: out[row][0:16] = x[row][:] @ W + b ----------------
// block: 256 rows; thread (rg,g) owns rows {rg+64j} x cols [4g,4g+4).
// x staged in LDS k-panels (KP=16, row stride 20 floats -> 2-addr/bank-quad),
// W resident whole in LDS. No cross-lane reduction.
template <int D>
__global__ __launch_bounds__(256) void encode_kernel(
    const float* __restrict__ x, const float* __restrict__ w,
    const float* __restrict__ bias, float* __restrict__ out, int nrows) {
    constexpr int KP = 16;
    __shared__ float wlds[D * 16];       // [k][16]
    __shared__ float xlds[256 * 20];     // [row][KP] stride 20 floats
    __shared__ float blds[16];

    for (int i = threadIdx.x; i < D * 4; i += 256)
        reinterpret_cast<float4*>(wlds)[i] =
            reinterpret_cast<const float4*>(w)[i];
    if (threadIdx.x < 16) blds[threadIdx.x] = bias[threadIdx.x];

    const int g = threadIdx.x & 3;
    const int rg = threadIdx.x >> 2;  // 0..63
    const int row0 = blockIdx.x * 256;

    float4 acc[4];
#pragma unroll
    for (int j = 0; j < 4; j++) acc[j] = make_float4(0.f, 0.f, 0.f, 0.f);

    for (int p = 0; p < D / KP; p++) {
        __syncthreads();
        // stage x panel: 256 rows x 16 k = 1024 float4; row = i>>2, q = i&3
        for (int i = threadIdx.x; i < 1024; i += 256) {
            const int rr = i >> 2, q = i & 3;
            const int grow = min(row0 + rr, nrows - 1);
            *reinterpret_cast<float4*>(xlds + rr * 20 + q * 4) =
                *reinterpret_cast<const float4*>(x + (size_t)grow * D +
                                                 p * KP + q * 4);
        }
        __syncthreads();
#pragma unroll
        for (int q = 0; q < KP / 4; q++) {
            const int k = p * KP + q * 4;
            const float4 w0 =
                *reinterpret_cast<const float4*>(wlds + (k + 0) * 16 + 4 * g);
            const float4 w1 =
                *reinterpret_cast<const float4*>(wlds + (k + 1) * 16 + 4 * g);
            const float4 w2 =
                *reinterpret_cast<const float4*>(wlds + (k + 2) * 16 + 4 * g);
            const float4 w3 =
                *reinterpret_cast<const float4*>(wlds + (k + 3) * 16 + 4 * g);
#pragma unroll
            for (int j = 0; j < 4; j++) {
                const float4 xv = *reinterpret_cast<const float4*>(
                    xlds + (rg + 64 * j) * 20 + q * 4);
                fma4(acc[j], xv.x, w0);
                fma4(acc[j], xv.y, w1);
                fma4(acc[j], xv.z, w2);
                fma4(acc[j], xv.w, w3);
            }
        }
    }

    const float4 b4 = *reinterpret_cast<const float4*>(blds + 4 * g);
#pragma unroll
    for (int j = 0; j < 4; j++) {
        const int grow = row0 + rg + 64 * j;
        if (grow < nrows) {
            float4 o;
            o.x = acc[j].x + b4.x;
            o.y = acc[j].y + b4.y;
            o.z = acc[j].z + b4.z;
            o.w = acc[j].w + b4.w;
            *reinterpret_cast<float4*>(out + (size_t)grow * 16 + 4 * g) = o;
        }
    }
}

// ---------------- CSR construction ----------------
__global__ __launch_bounds__(256) void hist_kernel(const int* __restrict__ dst,
                                                   int* __restrict__ cnt) {
    const int e = blockIdx.x * 256 + threadIdx.x;
    if (e >= ETRAIN) return;
    atomicAdd(cnt + dst[e], 1);
}

__global__ __launch_bounds__(256) void scan1_kernel(const int* __restrict__ in,
                                                    int* __restrict__ out,
                                                    int* __restrict__ bsum,
                                                    int n) {
    __shared__ int s[256];
    const int tid = threadIdx.x;
    const int i = blockIdx.x * 256 + tid;
    const int v = (i < n) ? in[i] : 0;
    s[tid] = v;
    __syncthreads();
#pragma unroll
    for (int off = 1; off < 256; off <<= 1) {
        const int t = (tid >= off) ? s[tid - off] : 0;
        __syncthreads();
        s[tid] += t;
        __syncthreads();
    }
    if (i < n) out[i] = s[tid] - v;
    if (tid == 255) bsum[blockIdx.x] = s[255];
}

__global__ __launch_bounds__(256) void scan2_kernel(int* __restrict__ bsum,
                                                    int nb) {
    __shared__ int s[256];
    const int tid = threadIdx.x;
    int carry = 0;
    for (int base = 0; base < nb; base += 256) {
        const int i = base + tid;
        const int v = (i < nb) ? bsum[i] : 0;
        s[tid] = v;
        __syncthreads();
#pragma unroll
        for (int off = 1; off < 256; off <<= 1) {
            const int t = (tid >= off) ? s[tid - off] : 0;
            __syncthreads();
            s[tid] += t;
            __syncthreads();
        }
        if (i < nb) bsum[i] = s[tid] - v + carry;
        const int tot = s[255];
        __syncthreads();
        carry += tot;
    }
}

__global__ __launch_bounds__(256) void scan3_kernel(int* __restrict__ out,
                                                    const int* __restrict__ bsum,
                                                    int n) {
    const int i = blockIdx.x * 256 + threadIdx.x;
    if (i < n) out[i] += bsum[blockIdx.x];
}

__global__ __launch_bounds__(256) void fill_kernel(
    const int* __restrict__ src, const int* __restrict__ dst,
    const int* __restrict__ et, const int* __restrict__ rowptr,
    int* __restrict__ fc, int* __restrict__ esorted) {
    const int e = blockIdx.x * 256 + threadIdx.x;
    if (e >= ETRAIN) return;
    const int d = dst[e];
    const int pos = rowptr[d] + atomicAdd(fc + d, 1);
    esorted[pos] = src[e] | (et[e] << 24);
}

// ---------------- RGCN phase A: per-relation feature sums ----------------
// thread-per-node: sx[n] = [ (1/deg)*sum_{t=0} x[src], (1/deg)*sum_{t=1} x[src] ]
template <int IN>
__global__ __launch_bounds__(256) void agg_kernel(
    const float* __restrict__ x, const int* __restrict__ rowptr,
    const int* __restrict__ cnt, const int* __restrict__ esorted,
    float* __restrict__ sx) {
    const int n = blockIdx.x * 256 + threadIdx.x;
    if (n >= NNODES) return;
    const int b = rowptr[n], c = cnt[n];

    float4 s0[IN / 4], s1[IN / 4];
#pragma unroll
    for (int q = 0; q < IN / 4; q++) {
        s0[q] = make_float4(0.f, 0.f, 0.f, 0.f);
        s1[q] = make_float4(0.f, 0.f, 0.f, 0.f);
    }

    int pk = (c > 0) ? esorted[b] : 0;
    for (int i = 0; i < c; i++) {
        const int pknext = (i + 1 < c) ? esorted[b + i + 1] : 0;
        const int s = pk & 0x00FFFFFF;
        const float w1 = (float)(pk >> 24);
        const float w0 = 1.0f - w1;
        const float4* xs =
            reinterpret_cast<const float4*>(x + (size_t)s * IN);
#pragma unroll
        for (int q = 0; q < IN / 4; q++) {
            const float4 xv = xs[q];
            fma4(s0[q], w0, xv);
            fma4(s1[q], w1, xv);
        }
        pk = pknext;
    }
    const float inv = 1.0f / fmaxf((float)c, 1.0f);
    float4* o = reinterpret_cast<float4*>(sx + (size_t)n * (2 * IN));
#pragma unroll
    for (int q = 0; q < IN / 4; q++) {
        float4 v = s0[q];
        v.x *= inv; v.y *= inv; v.z *= inv; v.w *= inv;
        o[q] = v;
    }
#pragma unroll
    for (int q = 0; q < IN / 4; q++) {
        float4 v = s1[q];
        v.x *= inv; v.y *= inv; v.z *= inv; v.w *= inv;
        o[IN / 4 + q] = v;
    }
}

// ---------------- RGCN phase B: out = [sx0,sx1,x] @ [W0;W1;root] + bias -----
template <int IN, int OUT, bool RELU>
__global__ __launch_bounds__(256) void combine2_kernel(
    const float* __restrict__ xin, const float* __restrict__ sx,
    const float* __restrict__ comp, const float* __restrict__ basis,
    const float* __restrict__ root, const float* __restrict__ bias,
    float* __restrict__ out) {
    constexpr int QP = OUT / 4;
    __shared__ float wl[3 * IN * OUT];  // rows: W0 | W1 | root
    __shared__ float bl[OUT];
    for (int i = threadIdx.x; i < 2 * IN * OUT; i += 256) {
        const int r = i / (IN * OUT);
        const int rem = i - r * IN * OUT;
        float v = 0.f;
#pragma unroll
        for (int bb = 0; bb < 4; bb++)
            v = fmaf(comp[r * 4 + bb], basis[bb * IN * OUT + rem], v);
        wl[i] = v;
    }
    for (int i = threadIdx.x; i < IN * OUT; i += 256)
        wl[2 * IN * OUT + i] = root[i];
    if (threadIdx.x < OUT) bl[threadIdx.x] = bias[threadIdx.x];
    __syncthreads();

    const int gtid = blockIdx.x * 256 + threadIdx.x;
    const int n = gtid / QP;
    const int g = gtid % QP;
    if (n >= NNODES) return;

    float4 acc = *reinterpret_cast<const float4*>(bl + 4 * g);

    const float4* iv1 =
        reinterpret_cast<const float4*>(sx + (size_t)n * (2 * IN));
#pragma unroll
    for (int q = 0; q < 2 * IN / 4; q++) {
        const float4 xv = iv1[q];
        const float* wr = wl + (q * 4) * OUT + 4 * g;
        fma4(acc, xv.x, *reinterpret_cast<const float4*>(wr));
        fma4(acc, xv.y, *reinterpret_cast<const float4*>(wr + OUT));
        fma4(acc, xv.z, *reinterpret_cast<const float4*>(wr + 2 * OUT));
        fma4(acc, xv.w, *reinterpret_cast<const float4*>(wr + 3 * OUT));
    }
    const float4* iv2 =
        reinterpret_cast<const float4*>(xin + (size_t)n * IN);
#pragma unroll
    for (int q = 0; q < IN / 4; q++) {
        const float4 xv = iv2[q];
        const float* wr = wl + (2 * IN + q * 4) * OUT + 4 * g;
        fma4(acc, xv.x, *reinterpret_cast<const float4*>(wr));
        fma4(acc, xv.y, *reinterpret_cast<const float4*>(wr + OUT));
        fma4(acc, xv.z, *reinterpret_cast<const float4*>(wr + 2 * OUT));
        fma4(acc, xv.w, *reinterpret_cast<const float4*>(wr + 3 * OUT));
    }
    if (RELU) {
        acc.x = fmaxf(acc.x, 0.f);
        acc.y = fmaxf(acc.y, 0.f);
        acc.z = fmaxf(acc.z, 0.f);
        acc.w = fmaxf(acc.w, 0.f);
    }
    reinterpret_cast<float4*>(out + (size_t)n * OUT)[g] = acc;
}

// ---------------- decode: score = ((zs @ W[t]) + b[t]) . zd ----------------
__global__ __launch_bounds__(256) void decode_kernel(
    const float* __restrict__ z, const int* __restrict__ ei,
    const int* __restrict__ et, const float* __restrict__ wp,
    const float* __restrict__ bp, const float* __restrict__ wm,
    const float* __restrict__ bm, float* __restrict__ out, int E) {
    __shared__ float wl[2 * 256];
    __shared__ float bl[2 * 16];
    {
        const int i = threadIdx.x;
        wl[i] = wp[i];
        wl[256 + i] = wm[i];
        if (i < 16) {
            bl[i] = bp[i];
            bl[16 + i] = bm[i];
        }
    }
    __syncthreads();

    const int e = blockIdx.x * 256 + threadIdx.x;
    if (e >= E) return;
    const int s = ei[e], d = ei[e + E], t = et[e];

    const float4* zs4 = reinterpret_cast<const float4*>(z + (size_t)s * 16);
    const float4* zd4 = reinterpret_cast<const float4*>(z + (size_t)d * 16);
    float4 zs[4], zd[4];
#pragma unroll
    for (int q = 0; q < 4; q++) {
        zs[q] = zs4[q];
        zd[q] = zd4[q];
    }

    const float* W = wl + t * 256;
    const float* B = bl + t * 16;
    float4 p[4];
#pragma unroll
    for (int g = 0; g < 4; g++) p[g] = reinterpret_cast<const float4*>(B)[g];

#pragma unroll
    for (int q = 0; q < 4; q++) {
        const float xs[4] = {zs[q].x, zs[q].y, zs[q].z, zs[q].w};
#pragma unroll
        for (int c = 0; c < 4; c++) {
            const float4* wr =
                reinterpret_cast<const float4*>(W + (q * 4 + c) * 16);
#pragma unroll
            for (int g = 0; g < 4; g++) fma4(p[g], xs[c], wr[g]);
        }
    }
    float sc = 0.f;
#pragma unroll
    for (int g = 0; g < 4; g++) {
        sc += p[g].x * zd[g].x + p[g].y * zd[g].y + p[g].z * zd[g].z +
              p[g].w * zd[g].w;
    }
    out[e] = sc;
}

extern "C" void kernel_launch(void* const* d_in, const int* in_sizes, int n_in,
                              void* d_out, int out_size, void* d_ws,
                              size_t ws_size, hipStream_t stream) {
    const float* x_paper = (const float*)d_in[0];
    const float* x_mesh = (const float*)d_in[1];
    const float* tp_w = (const float*)d_in[2];
    const float* tp_b = (const float*)d_in[3];
    const float* tm_w = (const float*)d_in[4];
    const float* tm_b = (const float*)d_in[5];
    const float* comp1 = (const float*)d_in[6];
    const float* basis1 = (const float*)d_in[7];
    const float* root1 = (const float*)d_in[8];
    const float* bias1 = (const float*)d_in[9];
    const float* comp2 = (const float*)d_in[10];
    const float* basis2 = (const float*)d_in[11];
    const float* root2 = (const float*)d_in[12];
    const float* bias2 = (const float*)d_in[13];
    const float* comp3 = (const float*)d_in[14];
    const float* basis3 = (const float*)d_in[15];
    const float* root3 = (const float*)d_in[16];
    const float* bias3 = (const float*)d_in[17];
    const float* dpp_w = (const float*)d_in[18];
    const float* dpp_b = (const float*)d_in[19];
    const float* dpm_w = (const float*)d_in[20];
    const float* dpm_b = (const float*)d_in[21];
    const int* tei = (const int*)d_in[22];
    const int* tet = (const int*)d_in[23];
    const int* pei = (const int*)d_in[24];
    const int* pet = (const int*)d_in[25];
    const int* nei = (const int*)d_in[26];
    const int* net = (const int*)d_in[27];
    float* out = (float*)d_out;

    // workspace layout (floats), with live-range overlays:
    //   R1 (32N): h1, later z (first 16N)
    //   R2 (32N): xfeat (first 16N), later h2
    //   R3 (64N): sx (per-layer scratch)
    float* ws = (float*)d_ws;
    float* R1 = ws;
    float* R2 = R1 + (size_t)NNODES * 32;
    float* R3 = R2 + (size_t)NNODES * 32;
    float* xfeat = R2;
    float* h1 = R1;
    float* h2 = R2;
    float* sx = R3;
    float* z = R1;

    int* rowptr = (int*)(R3 + (size_t)NNODES * 64);  // N
    int* ecnt = rowptr + NNODES;                     // N
    int* fc = ecnt + NNODES;                         // N
    int* esorted = fc + NNODES;                      // E_TRAIN
    int* bsum = esorted + ETRAIN;                    // ~1K

    const int* tsrc = tei;
    const int* tdst = tei + ETRAIN;

    const int eblocks = (ETRAIN + 255) / 256;
    const int nb = (NNODES + 255) / 256;  // 899

    // ---- encode ----
    encode_kernel<512><<<(NPAPER + 255) / 256, 256, 0, stream>>>(
        x_paper, tp_w, tp_b, xfeat, NPAPER);
    encode_kernel<128><<<(NMESH + 255) / 256, 256, 0, stream>>>(
        x_mesh, tm_w, tm_b, xfeat + (size_t)NPAPER * 16, NMESH);

    // ---- CSR build (once; reused by all 3 layers) ----
    hipMemsetAsync(ecnt, 0, (size_t)NNODES * 4, stream);
    hipMemsetAsync(fc, 0, (size_t)NNODES * 4, stream);
    hist_kernel<<<eblocks, 256, 0, stream>>>(tdst, ecnt);
    scan1_kernel<<<nb, 256, 0, stream>>>(ecnt, rowptr, bsum, NNODES);
    scan2_kernel<<<1, 256, 0, stream>>>(bsum, nb);
    scan3_kernel<<<nb, 256, 0, stream>>>(rowptr, bsum, NNODES);
    fill_kernel<<<eblocks, 256, 0, stream>>>(tsrc, tdst, tet, rowptr, fc,
                                             esorted);

    // ---- layer 1: 16 -> 32, relu ----
    agg_kernel<16><<<nb, 256, 0, stream>>>(xfeat, rowptr, ecnt, esorted, sx);
    combine2_kernel<16, 32, true>
        <<<(NNODES * 8 + 255) / 256, 256, 0, stream>>>(xfeat, sx, comp1,
                                                       basis1, root1, bias1,
                                                       h1);
    // ---- layer 2: 32 -> 32, relu ----
    agg_kernel<32><<<nb, 256, 0, stream>>>(h1, rowptr, ecnt, esorted, sx);
    combine2_kernel<32, 32, true>
        <<<(NNODES * 8 + 255) / 256, 256, 0, stream>>>(h1, sx, comp2, basis2,
                                                       root2, bias2, h2);
    // ---- layer 3: 32 -> 16, no relu ----
    agg_kernel<32><<<nb, 256, 0, stream>>>(h2, rowptr, ecnt, esorted, sx);
    combine2_kernel<32, 16, false>
        <<<(NNODES * 4 + 255) / 256, 256, 0, stream>>>(h2, sx, comp3, basis3,
                                                       root3, bias3, z);

    // ---- decode ----
    decode_kernel<<<(EPOS + 255) / 256, 256, 0, stream>>>(
        z, pei, pet, dpp_w, dpp_b, dpm_w, dpm_b, out, EPOS);
    decode_kernel<<<(ENEG + 255) / 256, 256, 0, stream>>>(
        z, nei, net, dpp_w, dpp_b, dpm_w, dpm_b, out + EPOS, ENEG);
}